// Round 7
// baseline (113.099 us; speedup 1.0000x reference)
//
#include <hip/hip_runtime.h>
#include <math.h>

#define TSIZE 32
#define WIN 11
#define NB 8
#define NG 16
#define NP 64
#define IMH 640
#define IMW 640
#define NBOX 640          // 128 gt + 512 pred
#define NPAIR 8192        // 8*16*64
#define K2GRID 1536

#define C1F 6.5025f
#define C2F 58.5225f

// group-rotate swizzle for 32x32 f32 tiles in LDS: row i, col-group jq(0..7)
// physical f4 slot = ((jq + i) & 7). Col-conv b128 reads cover all 32 banks
// per 8-lane row phase -> conflict-free; same for writes.
#define SWZ4(row, jq) (((row) << 5) + ((((jq) + (row)) & 7) << 2))

struct GaussW { float g[WIN]; };
struct f4 { float v[4]; };

__device__ __forceinline__ float shl(float v, int src) {
    src = src < 0 ? 0 : (src > 63 ? 63 : src);
    return __shfl(v, src, 64);
}

// Build 14-tap row window (cols j4-5 .. j4+8, zero outside [0,32)) from
// per-thread f4 via intra-row shuffles. t = lane&7 (col group in row).
__device__ __forceinline__ void row_window(
    const float* __restrict__ own, int lane, int t, float* __restrict__ pv)
{
    const int l = lane;
    const float a0 = shl(own[0], l - 1), a1 = shl(own[1], l - 1);
    const float a2 = shl(own[2], l - 1), a3 = shl(own[3], l - 1);
    const float b0 = shl(own[0], l + 1), b1 = shl(own[1], l + 1);
    const float b2 = shl(own[2], l + 1), b3 = shl(own[3], l + 1);
    const float m3 = shl(own[3], l - 2);   // col j4-5
    const float p0 = shl(own[0], l + 2);   // col j4+8
    const bool vm1 = (t >= 1), vm2 = (t >= 2);
    const bool vp1 = (t <= 6), vp2 = (t <= 5);
    pv[0]  = vm2 ? m3 : 0.0f;
    pv[1]  = vm1 ? a0 : 0.0f;
    pv[2]  = vm1 ? a1 : 0.0f;
    pv[3]  = vm1 ? a2 : 0.0f;
    pv[4]  = vm1 ? a3 : 0.0f;
    pv[5]  = own[0]; pv[6] = own[1]; pv[7] = own[2]; pv[8] = own[3];
    pv[9]  = vp1 ? b0 : 0.0f;
    pv[10] = vp1 ? b1 : 0.0f;
    pv[11] = vp1 ? b2 : 0.0f;
    pv[12] = vp1 ? b3 : 0.0f;
    pv[13] = vp2 ? p0 : 0.0f;
}

__device__ __forceinline__ bool iou_mask(
    const float* __restrict__ gt_boxes, const float* __restrict__ pred_boxes,
    int p)
{
#pragma clang fp contract(off)
    const int b  = p >> 10;
    const int gi = (p >> 6) & 15;
    const int pi = p & 63;
    const float* gb = gt_boxes  + ((size_t)b * NG + gi) * 4;
    const float* pb = pred_boxes + ((size_t)b * NP + pi) * 4;
    const float gx = gb[0], gy = gb[1], gw_ = gb[2], gh = gb[3];
    const float px = pb[0], py = pb[1], pw = pb[2], ph = pb[3];
    const float tlx = fmaxf(gx - gw_ / 2.0f, px - pw / 2.0f);
    const float tly = fmaxf(gy - gh / 2.0f, py - ph / 2.0f);
    const float brx = fminf(gx + gw_ / 2.0f, px + pw / 2.0f);
    const float bry = fminf(gy + gh / 2.0f, py + ph / 2.0f);
    const float en = ((tlx < brx) ? 1.0f : 0.0f) * ((tly < bry) ? 1.0f : 0.0f);
    const float ai = ((brx - tlx) * (bry - tly)) * en;
    const float ag = gw_ * gh;
    const float ap = pw * ph;
    const float iou = ai / (ag + ap - ai + 1e-16f);
    return (iou > 0.3f) && (pw > 2.0f) && (ph > 2.0f);
}

// ---------------------------------------------------------------------------
// K1: blocks [0,1920): one block per (box,channel): pipelined crop staging ->
// LDS, bilinear -> regs, shuffle row conv, swizzled-LDS col conv.
// block 1920: single-block compaction of the IoU mask into a globally
// contiguous pair_list (ascending p order) + total count. No atomics/memset.
// ---------------------------------------------------------------------------
__global__ __launch_bounds__(256) void gen_patches(
    const float* __restrict__ gt_boxes, const float* __restrict__ pred_boxes,
    const float* __restrict__ imgs,
    float* __restrict__ patches, float* __restrict__ mus, float* __restrict__ gsqs,
    int* __restrict__ pair_list, int* __restrict__ pair_cnt, GaussW gw)
{
    const int bid = blockIdx.x;
    const int tid = threadIdx.x;

    if (bid >= NBOX * 3) {
        // ---- single-block globally-compacted mask scan ----
        __shared__ int wcnt[4], woff[4], s_base;
        const int lane = tid & 63, wid = tid >> 6;
        int base = 0;
        for (int it = 0; it < NPAIR / 256; ++it) {
            const int p = it * 256 + tid;
            const bool mask = iou_mask(gt_boxes, pred_boxes, p);
            const unsigned long long bal = __ballot(mask);
            if (lane == 0) wcnt[wid] = __popcll(bal);
            __syncthreads();
            if (tid == 0) {
                int s = base;
#pragma unroll
                for (int w = 0; w < 4; ++w) { woff[w] = s; s += wcnt[w]; }
                s_base = s;
            }
            __syncthreads();
            if (mask) {
                const int pre = __popcll(bal & ((1ull << lane) - 1ull));
                pair_list[woff[wid] + pre] = p;
            }
            base = s_base;
            __syncthreads();   // wcnt/woff reuse next iteration
        }
        if (tid == 0) pair_cnt[0] = base;
        return;
    }

    // ---- patch generation ----
    const int box = bid / 3;
    const int c   = bid - box * 3;
    int b;
    const float* boxp;
    if (box < NB * NG) {
        b = box >> 4;
        boxp = gt_boxes + (size_t)box * 4;
    } else {
        const int q = box - NB * NG;
        b = q >> 6;
        boxp = pred_boxes + (size_t)q * 4;
    }
    const float* __restrict__ ic = imgs + ((size_t)b * 3 + c) * (IMH * IMW);
    float* __restrict__ patch_o = patches + ((size_t)box * 3 + c) * 1024;
    float* __restrict__ mu_o    = mus     + ((size_t)box * 3 + c) * 1024;
    float* __restrict__ gsq_o   = gsqs    + ((size_t)box * 3 + c) * 1024;

    __shared__ int   s_ylo[TSIZE], s_yhi[TSIZE], s_xlo[TSIZE], s_xhi[TSIZE];
    __shared__ float s_wy[TSIZE], s_wx[TSIZE];
    __shared__ __align__(16) float smem[4704];  // crop region; later ta/tb
    float* const ta = smem;
    float* const tb = smem + 1024;

    {
#pragma clang fp contract(off)
        const float b0 = boxp[0], b1 = boxp[1], b2 = boxp[2], b3 = boxp[3];
        const float x0 = floorf(b0), y0 = floorf(b1);
        const float w = floorf(b0 + b2) - x0;
        const float h = floorf(b1 + b3) - y0;

        if (tid < TSIZE) {
            const int t = tid;
            const float hm = fmaxf(h - 1.0f, 0.0f);
            const float scale = h / 32.0f;
            float ys = ((float)t + 0.5f) * scale - 0.5f;
            ys = fminf(fmaxf(ys, 0.0f), hm);
            const float yf = floorf(ys);
            s_wy[t] = ys - yf;
            const float ylo = yf + y0;
            const float yhi = fminf(yf + 1.0f, hm) + y0;
            s_ylo[t] = (int)fminf(fmaxf(ylo, 0.0f), (float)(IMH - 1));
            s_yhi[t] = (int)fminf(fmaxf(yhi, 0.0f), (float)(IMH - 1));
        } else if (tid < 2 * TSIZE) {
            const int t = tid - TSIZE;
            const float wm = fmaxf(w - 1.0f, 0.0f);
            const float scale = w / 32.0f;
            float xs = ((float)t + 0.5f) * scale - 0.5f;
            xs = fminf(fmaxf(xs, 0.0f), wm);
            const float xf = floorf(xs);
            s_wx[t] = xs - xf;
            const float xlo = xf + x0;
            const float xhi = fminf(xf + 1.0f, wm) + x0;
            s_xlo[t] = (int)fminf(fmaxf(xlo, 0.0f), (float)(IMW - 1));
            s_xhi[t] = (int)fminf(fmaxf(xhi, 0.0f), (float)(IMW - 1));
        }
    }
    __syncthreads();

    // stage crop region: two-phase (all loads in flight, then LDS writes)
    const int ry0 = s_ylo[0], ry1 = s_yhi[31];
    const int rx0 = s_xlo[0], rx1 = s_xhi[31];
    const int RH = ry1 - ry0 + 1;                // <= 69
    const int RW = rx1 - rx0 + 1;                // <= 69
    const int stride = RW | 1;
    const int wv = tid >> 6, lane = tid & 63;
    {
        float rbuf[18];
        const bool cl = lane < RW;
#pragma unroll
        for (int u = 0; u < 18; ++u) {
            const int r = wv + (u << 2);
            rbuf[u] = (r < RH && cl)
                      ? ic[(size_t)(ry0 + r) * IMW + rx0 + lane] : 0.0f;
        }
        const bool c2 = (64 + lane) < RW;        // rare tail cols
#pragma unroll
        for (int u = 0; u < 18; ++u) {
            const int r = wv + (u << 2);
            if (r < RH) {
                if (cl) smem[r * stride + lane] = rbuf[u];
                if (c2) smem[r * stride + 64 + lane] =
                            ic[(size_t)(ry0 + r) * IMW + rx0 + 64 + lane];
            }
        }
    }
    __syncthreads();

    const int i  = tid >> 3;            // row 0..31 (8 threads per row)
    const int t  = tid & 7;             // col group in row
    const int j4 = t << 2;
    const int jq = t;
    const int e4 = (i << 5) + j4;

    // bilinear from LDS crop -> registers
    float vv[4];
    {
        const int yl = s_ylo[i] - ry0, yh = s_yhi[i] - ry0;
        const float wy = s_wy[i];
#pragma unroll
        for (int q = 0; q < 4; ++q) {
#pragma clang fp contract(off)
            const int j = j4 + q;
            const int xl = s_xlo[j] - rx0, xh = s_xhi[j] - rx0;
            const float wx = s_wx[j];
            const float tl = smem[yl * stride + xl], tr = smem[yl * stride + xh];
            const float bl = smem[yh * stride + xl], br = smem[yh * stride + xh];
            const float top = tl * (1.0f - wx) + tr * wx;
            const float bot = bl * (1.0f - wx) + br * wx;
            vv[q] = top * (1.0f - wy) + bot * wy;
        }
    }
    __syncthreads();   // all crop reads done before aliasing smem as ta/tb

    {
        f4 o; o.v[0] = vv[0]; o.v[1] = vv[1]; o.v[2] = vv[2]; o.v[3] = vv[3];
        *(f4*)&patch_o[e4] = o;
    }

    // row conv (val, val^2) via shuffles -> swizzled ta/tb
    {
        float pv[14];
        row_window(vv, lane, t, pv);
        float am[4] = {0.f,0.f,0.f,0.f}, aq[4] = {0.f,0.f,0.f,0.f};
#pragma unroll
        for (int k = 0; k < WIN; ++k) {
            const float gk = gw.g[k];
#pragma unroll
            for (int q = 0; q < 4; ++q) {
                const float v = pv[k + q];
                am[q] += gk * v;
                aq[q] += gk * (v * v);
            }
        }
        f4 oa, ob;
#pragma unroll
        for (int q = 0; q < 4; ++q) { oa.v[q] = am[q]; ob.v[q] = aq[q]; }
        *(f4*)&ta[SWZ4(i, jq)] = oa;
        *(f4*)&tb[SWZ4(i, jq)] = ob;
    }
    __syncthreads();

    // col conv from swizzled LDS (b128, conflict-free)
    {
        float cm[4] = {0.f,0.f,0.f,0.f}, cq[4] = {0.f,0.f,0.f,0.f};
#pragma unroll
        for (int k = 0; k < WIN; ++k) {
            const int ii = i - 5 + k;
            if (ii >= 0 && ii < TSIZE) {
                const float gk = gw.g[k];
                const f4 m4 = *(const f4*)&ta[SWZ4(ii, jq)];
                const f4 s4 = *(const f4*)&tb[SWZ4(ii, jq)];
#pragma unroll
                for (int q = 0; q < 4; ++q) {
                    cm[q] += gk * m4.v[q];
                    cq[q] += gk * s4.v[q];
                }
            }
        }
        f4 om, oq;
#pragma unroll
        for (int q = 0; q < 4; ++q) { om.v[q] = cm[q]; oq.v[q] = cq[q]; }
        *(f4*)&mu_o[e4]  = om;
        *(f4*)&gsq_o[e4] = oq;
    }
}

// ---------------------------------------------------------------------------
// K2: grid-stride over (active pair, channel), direct compacted pair_list.
// x,y in registers; xy row conv via shuffles; swizzled-LDS col conv; fused
// SSIM+L1; partial[w] write. No atomics, no fences, no per-block scan.
// ---------------------------------------------------------------------------
__global__ __launch_bounds__(256) void pair_kernel(
    const float* __restrict__ patches, const float* __restrict__ mus,
    const float* __restrict__ gsqs,
    const int* __restrict__ pair_list, const int* __restrict__ pair_cnt,
    float* __restrict__ partial, GaussW gw)
{
    __shared__ __align__(16) float tp[1024];
    __shared__ float wred[4];
    const int tid = threadIdx.x;
    const int nw = pair_cnt[0] * 3;    // uniform scalar load

    const int i  = tid >> 3;
    const int t  = tid & 7;
    const int j4 = t << 2;
    const int jq = t;
    const int e4 = (i << 5) + j4;
    const int lane = tid & 63;

    for (int w = blockIdx.x; w < nw; w += gridDim.x) {
        const int k3 = w / 3;
        const int c  = w - k3 * 3;
        const int p  = pair_list[k3];
        const int b  = p >> 10;
        const int gi = (p >> 6) & 15;
        const int pi = p & 63;
        const int gbox = b * NG + gi;
        const int pbox = NB * NG + b * NP + pi;
        const size_t po = ((size_t)pbox * 3 + c) * 1024;
        const size_t go = ((size_t)gbox * 3 + c) * 1024;

        const f4 xv = *(const f4*)&patches[po + e4];
        const f4 yv = *(const f4*)&patches[go + e4];

        // row conv of x*y via shuffles -> swizzled tp
        {
            float prod[4];
#pragma unroll
            for (int q = 0; q < 4; ++q) prod[q] = xv.v[q] * yv.v[q];
            float pv[14];
            row_window(prod, lane, t, pv);
            float a[4] = {0.f,0.f,0.f,0.f};
#pragma unroll
            for (int k = 0; k < WIN; ++k) {
                const float gk = gw.g[k];
#pragma unroll
                for (int q = 0; q < 4; ++q) a[q] += gk * pv[k + q];
            }
            f4 o;
#pragma unroll
            for (int q = 0; q < 4; ++q) o.v[q] = a[q];
            *(f4*)&tp[SWZ4(i, jq)] = o;
        }
        __syncthreads();

        // col conv + fused epilogue
        float lsum = 0.0f;
        {
            float cxy[4] = {0.f,0.f,0.f,0.f};
#pragma unroll
            for (int k = 0; k < WIN; ++k) {
                const int ii = i - 5 + k;
                if (ii >= 0 && ii < TSIZE) {
                    const float gk = gw.g[k];
                    const f4 t4 = *(const f4*)&tp[SWZ4(ii, jq)];
#pragma unroll
                    for (int q = 0; q < 4; ++q) cxy[q] += gk * t4.v[q];
                }
            }
            const f4 mu1 = *(const f4*)&mus[po + e4];
            const f4 mu2 = *(const f4*)&mus[go + e4];
            const f4 q1  = *(const f4*)&gsqs[po + e4];
            const f4 q2  = *(const f4*)&gsqs[go + e4];
#pragma unroll
            for (int q = 0; q < 4; ++q) {
                const float m1 = mu1.v[q], m2 = mu2.v[q];
                const float m1s = m1 * m1, m2s = m2 * m2, m12 = m1 * m2;
                const float s1  = q1.v[q] - m1s;
                const float s2  = q2.v[q] - m2s;
                const float s12 = cxy[q] - m12;
                const float num = (2.0f * m12 + C1F) * (2.0f * s12 + C2F);
                const float den = (m1s + m2s + C1F) * (s1 + s2 + C2F);
                const float ssim = num / den;
                lsum += fabsf(xv.v[q] / 255.0f - yv.v[q] / 255.0f) + (1.0f - ssim);
            }
        }

        // block reduce, atomic-free partial write
#pragma unroll
        for (int off = 32; off > 0; off >>= 1) lsum += __shfl_down(lsum, off);
        if (lane == 0) wred[tid >> 6] = lsum;
        __syncthreads();
        if (tid == 0) partial[w] = wred[0] + wred[1] + wred[2] + wred[3];
        __syncthreads();   // protect tp/wred reuse on next iteration
    }
}

__global__ __launch_bounds__(256) void finalize_kernel(
    const int* __restrict__ pair_cnt, const float* __restrict__ partial,
    float* __restrict__ out)
{
    __shared__ float wred[4];
    const int tid = threadIdx.x;
    const int n = pair_cnt[0];
    const int nw = n * 3;
    float lsum = 0.0f;
    for (int w = tid; w < nw; w += 256) lsum += partial[w];
#pragma unroll
    for (int off = 32; off > 0; off >>= 1) lsum += __shfl_down(lsum, off);
    if ((tid & 63) == 0) wred[tid >> 6] = lsum;
    __syncthreads();
    if (tid == 0) {
        const float total = wred[0] + wred[1] + wred[2] + wred[3];
        out[0] = (n > 0) ? (total / ((float)n * 3072.0f)) : 0.0f;
    }
}

extern "C" void kernel_launch(void* const* d_in, const int* in_sizes, int n_in,
                              void* d_out, int out_size, void* d_ws, size_t ws_size,
                              hipStream_t stream) {
    const float* gt_boxes   = (const float*)d_in[0];  // (8,16,4)
    const float* pred_boxes = (const float*)d_in[1];  // (8,64,4)
    const float* imgs       = (const float*)d_in[2];  // (8,3,640,640)

    GaussW gw;
    {
        double gd[WIN]; double s = 0.0;
        for (int k = 0; k < WIN; ++k) {
            const double d = (double)(k - WIN / 2);
            gd[k] = exp(-(d * d) / (2.0 * 1.5 * 1.5));
            s += gd[k];
        }
        for (int k = 0; k < WIN; ++k) gw.g[k] = (float)(gd[k] / s);
    }

    float* ws = (float*)d_ws;
    float* patches = ws;                               // 640*3072
    float* mus     = patches + (size_t)NBOX * 3072;
    float* gsqs    = mus     + (size_t)NBOX * 3072;
    float* partial = gsqs    + (size_t)NBOX * 3072;    // 3*8192
    int* pair_list = (int*)(partial + 3 * NPAIR);      // 8192
    int* pair_cnt  = pair_list + NPAIR;                // 1

    gen_patches<<<NBOX * 3 + 1, 256, 0, stream>>>(
        gt_boxes, pred_boxes, imgs, patches, mus, gsqs, pair_list, pair_cnt, gw);

    pair_kernel<<<K2GRID, 256, 0, stream>>>(
        patches, mus, gsqs, pair_list, pair_cnt, partial, gw);

    finalize_kernel<<<1, 256, 0, stream>>>(pair_cnt, partial, (float*)d_out);
}

// Round 8
// 112.859 us; speedup vs baseline: 1.0021x; 1.0021x over previous
//
#include <hip/hip_runtime.h>
#include <math.h>

#define TSIZE 32
#define WIN 11
#define NB 8
#define NG 16
#define NP 64
#define IMH 640
#define IMW 640
#define NBOX 640          // 128 gt + 512 pred
#define NPAIR 8192        // 8*16*64
#define NCOMP (NPAIR/256) // 32 compaction blocks
#define K2GRID 1536

#define C1F 6.5025f
#define C2F 58.5225f

// group-rotate swizzle for 32x32 f32 tiles in LDS: row i, col-group jq(0..7)
// physical f4 slot = ((jq + i) & 7). Col-conv b128 reads cover all 32 banks
// per 8-lane row phase -> conflict-free; same for writes.
#define SWZ4(row, jq) (((row) << 5) + ((((jq) + (row)) & 7) << 2))

struct GaussW { float g[WIN]; };
struct f4 { float v[4]; };

__device__ __forceinline__ float shl(float v, int src) {
    src = src < 0 ? 0 : (src > 63 ? 63 : src);
    return __shfl(v, src, 64);
}

// Build 14-tap row window (cols j4-5 .. j4+8, zero outside [0,32)) from
// per-thread f4 via intra-row shuffles. t = lane&7 (col group in row).
__device__ __forceinline__ void row_window(
    const float* __restrict__ own, int lane, int t, float* __restrict__ pv)
{
    const int l = lane;
    const float a0 = shl(own[0], l - 1), a1 = shl(own[1], l - 1);
    const float a2 = shl(own[2], l - 1), a3 = shl(own[3], l - 1);
    const float b0 = shl(own[0], l + 1), b1 = shl(own[1], l + 1);
    const float b2 = shl(own[2], l + 1), b3 = shl(own[3], l + 1);
    const float m3 = shl(own[3], l - 2);   // col j4-5
    const float p0 = shl(own[0], l + 2);   // col j4+8
    const bool vm1 = (t >= 1), vm2 = (t >= 2);
    const bool vp1 = (t <= 6), vp2 = (t <= 5);
    pv[0]  = vm2 ? m3 : 0.0f;
    pv[1]  = vm1 ? a0 : 0.0f;
    pv[2]  = vm1 ? a1 : 0.0f;
    pv[3]  = vm1 ? a2 : 0.0f;
    pv[4]  = vm1 ? a3 : 0.0f;
    pv[5]  = own[0]; pv[6] = own[1]; pv[7] = own[2]; pv[8] = own[3];
    pv[9]  = vp1 ? b0 : 0.0f;
    pv[10] = vp1 ? b1 : 0.0f;
    pv[11] = vp1 ? b2 : 0.0f;
    pv[12] = vp1 ? b3 : 0.0f;
    pv[13] = vp2 ? p0 : 0.0f;
}

// ---------------------------------------------------------------------------
// K1: blocks [0,1920): one block per (box,channel): pipelined crop staging ->
// LDS, bilinear -> regs, shuffle row conv, swizzled-LDS col conv.
// blocks [1920,1952): parallel ballot-compaction into per-block sublists
// (no atomics, no zero-init). Block 1920 also zeroes d_out for K2's atomics
// (visible across the dispatch boundary).
// ---------------------------------------------------------------------------
__global__ __launch_bounds__(256) void gen_patches(
    const float* __restrict__ gt_boxes, const float* __restrict__ pred_boxes,
    const float* __restrict__ imgs,
    float* __restrict__ patches, float* __restrict__ mus, float* __restrict__ gsqs,
    int* __restrict__ pair_list, int* __restrict__ pair_cnt,
    float* __restrict__ out, GaussW gw)
{
    const int bid = blockIdx.x;
    const int tid = threadIdx.x;

    if (bid >= NBOX * 3) {
        // ---- per-block ballot compaction ----
        const int blk = bid - NBOX * 3;          // [0, 32)
        if (blk == 0 && tid == 0) out[0] = 0.0f;
        const int p = blk * 256 + tid;           // [0, 8192)
        const int b  = p >> 10;
        const int gi = (p >> 6) & 15;
        const int pi = p & 63;
        bool mask;
        {
#pragma clang fp contract(off)
            const float* gb = gt_boxes  + ((size_t)b * NG + gi) * 4;
            const float* pb = pred_boxes + ((size_t)b * NP + pi) * 4;
            const float gx = gb[0], gy = gb[1], gw_ = gb[2], gh = gb[3];
            const float px = pb[0], py = pb[1], pw = pb[2], ph = pb[3];
            const float tlx = fmaxf(gx - gw_ / 2.0f, px - pw / 2.0f);
            const float tly = fmaxf(gy - gh / 2.0f, py - ph / 2.0f);
            const float brx = fminf(gx + gw_ / 2.0f, px + pw / 2.0f);
            const float bry = fminf(gy + gh / 2.0f, py + ph / 2.0f);
            const float en = ((tlx < brx) ? 1.0f : 0.0f) * ((tly < bry) ? 1.0f : 0.0f);
            const float ai = ((brx - tlx) * (bry - tly)) * en;
            const float ag = gw_ * gh;
            const float ap = pw * ph;
            const float iou = ai / (ag + ap - ai + 1e-16f);
            mask = (iou > 0.3f) && (pw > 2.0f) && (ph > 2.0f);
        }
        __shared__ int wcnt[4], woff[4];
        const unsigned long long bal = __ballot(mask);
        const int lane = tid & 63, wid = tid >> 6;
        if (lane == 0) wcnt[wid] = __popcll(bal);
        __syncthreads();
        if (tid == 0) {
            int s = 0;
#pragma unroll
            for (int w = 0; w < 4; ++w) { woff[w] = s; s += wcnt[w]; }
            pair_cnt[blk] = s;
        }
        __syncthreads();
        if (mask) {
            const int pre = __popcll(bal & ((1ull << lane) - 1ull));
            pair_list[blk * 256 + woff[wid] + pre] = p;
        }
        return;
    }

    // ---- patch generation ----
    const int box = bid / 3;
    const int c   = bid - box * 3;
    int b;
    const float* boxp;
    if (box < NB * NG) {
        b = box >> 4;
        boxp = gt_boxes + (size_t)box * 4;
    } else {
        const int q = box - NB * NG;
        b = q >> 6;
        boxp = pred_boxes + (size_t)q * 4;
    }
    const float* __restrict__ ic = imgs + ((size_t)b * 3 + c) * (IMH * IMW);
    float* __restrict__ patch_o = patches + ((size_t)box * 3 + c) * 1024;
    float* __restrict__ mu_o    = mus     + ((size_t)box * 3 + c) * 1024;
    float* __restrict__ gsq_o   = gsqs    + ((size_t)box * 3 + c) * 1024;

    __shared__ int   s_ylo[TSIZE], s_yhi[TSIZE], s_xlo[TSIZE], s_xhi[TSIZE];
    __shared__ float s_wy[TSIZE], s_wx[TSIZE];
    __shared__ __align__(16) float smem[4704];  // crop region; later ta/tb
    float* const ta = smem;
    float* const tb = smem + 1024;

    {
#pragma clang fp contract(off)
        const float b0 = boxp[0], b1 = boxp[1], b2 = boxp[2], b3 = boxp[3];
        const float x0 = floorf(b0), y0 = floorf(b1);
        const float w = floorf(b0 + b2) - x0;
        const float h = floorf(b1 + b3) - y0;

        if (tid < TSIZE) {
            const int t = tid;
            const float hm = fmaxf(h - 1.0f, 0.0f);
            const float scale = h / 32.0f;
            float ys = ((float)t + 0.5f) * scale - 0.5f;
            ys = fminf(fmaxf(ys, 0.0f), hm);
            const float yf = floorf(ys);
            s_wy[t] = ys - yf;
            const float ylo = yf + y0;
            const float yhi = fminf(yf + 1.0f, hm) + y0;
            s_ylo[t] = (int)fminf(fmaxf(ylo, 0.0f), (float)(IMH - 1));
            s_yhi[t] = (int)fminf(fmaxf(yhi, 0.0f), (float)(IMH - 1));
        } else if (tid < 2 * TSIZE) {
            const int t = tid - TSIZE;
            const float wm = fmaxf(w - 1.0f, 0.0f);
            const float scale = w / 32.0f;
            float xs = ((float)t + 0.5f) * scale - 0.5f;
            xs = fminf(fmaxf(xs, 0.0f), wm);
            const float xf = floorf(xs);
            s_wx[t] = xs - xf;
            const float xlo = xf + x0;
            const float xhi = fminf(xf + 1.0f, wm) + x0;
            s_xlo[t] = (int)fminf(fmaxf(xlo, 0.0f), (float)(IMW - 1));
            s_xhi[t] = (int)fminf(fmaxf(xhi, 0.0f), (float)(IMW - 1));
        }
    }
    __syncthreads();

    // stage crop region: two-phase (all loads in flight, then LDS writes)
    const int ry0 = s_ylo[0], ry1 = s_yhi[31];
    const int rx0 = s_xlo[0], rx1 = s_xhi[31];
    const int RH = ry1 - ry0 + 1;                // <= 69
    const int RW = rx1 - rx0 + 1;                // <= 69
    const int stride = RW | 1;
    const int wv = tid >> 6, lane = tid & 63;
    {
        float rbuf[18];
        const bool cl = lane < RW;
#pragma unroll
        for (int u = 0; u < 18; ++u) {
            const int r = wv + (u << 2);
            rbuf[u] = (r < RH && cl)
                      ? ic[(size_t)(ry0 + r) * IMW + rx0 + lane] : 0.0f;
        }
        const bool c2 = (64 + lane) < RW;        // rare tail cols
#pragma unroll
        for (int u = 0; u < 18; ++u) {
            const int r = wv + (u << 2);
            if (r < RH) {
                if (cl) smem[r * stride + lane] = rbuf[u];
                if (c2) smem[r * stride + 64 + lane] =
                            ic[(size_t)(ry0 + r) * IMW + rx0 + 64 + lane];
            }
        }
    }
    __syncthreads();

    const int i  = tid >> 3;            // row 0..31 (8 threads per row)
    const int t  = tid & 7;             // col group in row
    const int j4 = t << 2;
    const int jq = t;
    const int e4 = (i << 5) + j4;

    // bilinear from LDS crop -> registers
    float vv[4];
    {
        const int yl = s_ylo[i] - ry0, yh = s_yhi[i] - ry0;
        const float wy = s_wy[i];
#pragma unroll
        for (int q = 0; q < 4; ++q) {
#pragma clang fp contract(off)
            const int j = j4 + q;
            const int xl = s_xlo[j] - rx0, xh = s_xhi[j] - rx0;
            const float wx = s_wx[j];
            const float tl = smem[yl * stride + xl], tr = smem[yl * stride + xh];
            const float bl = smem[yh * stride + xl], br = smem[yh * stride + xh];
            const float top = tl * (1.0f - wx) + tr * wx;
            const float bot = bl * (1.0f - wx) + br * wx;
            vv[q] = top * (1.0f - wy) + bot * wy;
        }
    }
    __syncthreads();   // all crop reads done before aliasing smem as ta/tb

    {
        f4 o; o.v[0] = vv[0]; o.v[1] = vv[1]; o.v[2] = vv[2]; o.v[3] = vv[3];
        *(f4*)&patch_o[e4] = o;
    }

    // row conv (val, val^2) via shuffles -> swizzled ta/tb
    {
        float pv[14];
        row_window(vv, lane, t, pv);
        float am[4] = {0.f,0.f,0.f,0.f}, aq[4] = {0.f,0.f,0.f,0.f};
#pragma unroll
        for (int k = 0; k < WIN; ++k) {
            const float gk = gw.g[k];
#pragma unroll
            for (int q = 0; q < 4; ++q) {
                const float v = pv[k + q];
                am[q] += gk * v;
                aq[q] += gk * (v * v);
            }
        }
        f4 oa, ob;
#pragma unroll
        for (int q = 0; q < 4; ++q) { oa.v[q] = am[q]; ob.v[q] = aq[q]; }
        *(f4*)&ta[SWZ4(i, jq)] = oa;
        *(f4*)&tb[SWZ4(i, jq)] = ob;
    }
    __syncthreads();

    // col conv from swizzled LDS (b128, conflict-free)
    {
        float cm[4] = {0.f,0.f,0.f,0.f}, cq[4] = {0.f,0.f,0.f,0.f};
#pragma unroll
        for (int k = 0; k < WIN; ++k) {
            const int ii = i - 5 + k;
            if (ii >= 0 && ii < TSIZE) {
                const float gk = gw.g[k];
                const f4 m4 = *(const f4*)&ta[SWZ4(ii, jq)];
                const f4 s4 = *(const f4*)&tb[SWZ4(ii, jq)];
#pragma unroll
                for (int q = 0; q < 4; ++q) {
                    cm[q] += gk * m4.v[q];
                    cq[q] += gk * s4.v[q];
                }
            }
        }
        f4 om, oq;
#pragma unroll
        for (int q = 0; q < 4; ++q) { om.v[q] = cm[q]; oq.v[q] = cq[q]; }
        *(f4*)&mu_o[e4]  = om;
        *(f4*)&gsq_o[e4] = oq;
    }
}

// ---------------------------------------------------------------------------
// K2: grid-stride over (active pair, channel). Parallel shuffle-prefix of the
// 32 per-block counts; x,y in registers; xy row conv via shuffles; swizzled-
// LDS col conv; fused SSIM+L1. One scaled atomicAdd per block into out
// (out zeroed by K1 across the dispatch boundary). NO finalize dispatch.
// ---------------------------------------------------------------------------
__global__ __launch_bounds__(256) void pair_kernel(
    const float* __restrict__ patches, const float* __restrict__ mus,
    const float* __restrict__ gsqs,
    const int* __restrict__ pair_list, const int* __restrict__ pair_cnt,
    float* __restrict__ out, GaussW gw)
{
    __shared__ __align__(16) float tp[1024];
    __shared__ float wred[4];
    __shared__ int cum[NCOMP + 1];
    const int tid = threadIdx.x;
    const int lane = tid & 63;

    // parallel prefix of 32 counts in wave 0 (~50 cyc)
    if (tid < 64) {
        int v = (lane < NCOMP) ? pair_cnt[lane] : 0;
#pragma unroll
        for (int d = 1; d < 32; d <<= 1) {
            const int u = __shfl_up(v, d, 64);
            if ((lane & 31) >= d) v += u;
        }
        if (lane < NCOMP) cum[lane + 1] = v;   // inclusive
        if (lane == 0) cum[0] = 0;
    }
    __syncthreads();
    const int n  = cum[NCOMP];
    const int nw = n * 3;
    const float inv_den = (n > 0) ? 1.0f / ((float)n * 3072.0f) : 0.0f;

    const int i  = tid >> 3;
    const int t  = tid & 7;
    const int j4 = t << 2;
    const int jq = t;
    const int e4 = (i << 5) + j4;

    float bsum = 0.0f;   // this block's accumulated loss over its items

    for (int w = blockIdx.x; w < nw; w += gridDim.x) {
        const int k3 = w / 3;
        const int c  = w - k3 * 3;
        int s = 0;
        while (cum[s + 1] <= k3) ++s;           // block-uniform, <=32 iters
        const int p  = pair_list[s * 256 + (k3 - cum[s])];
        const int b  = p >> 10;
        const int gi = (p >> 6) & 15;
        const int pi = p & 63;
        const int gbox = b * NG + gi;
        const int pbox = NB * NG + b * NP + pi;
        const size_t po = ((size_t)pbox * 3 + c) * 1024;
        const size_t go = ((size_t)gbox * 3 + c) * 1024;

        const f4 xv = *(const f4*)&patches[po + e4];
        const f4 yv = *(const f4*)&patches[go + e4];

        // row conv of x*y via shuffles -> swizzled tp
        {
            float prod[4];
#pragma unroll
            for (int q = 0; q < 4; ++q) prod[q] = xv.v[q] * yv.v[q];
            float pv[14];
            row_window(prod, lane, t, pv);
            float a[4] = {0.f,0.f,0.f,0.f};
#pragma unroll
            for (int k = 0; k < WIN; ++k) {
                const float gk = gw.g[k];
#pragma unroll
                for (int q = 0; q < 4; ++q) a[q] += gk * pv[k + q];
            }
            f4 o;
#pragma unroll
            for (int q = 0; q < 4; ++q) o.v[q] = a[q];
            *(f4*)&tp[SWZ4(i, jq)] = o;
        }
        __syncthreads();

        // col conv + fused epilogue
        float lsum = 0.0f;
        {
            float cxy[4] = {0.f,0.f,0.f,0.f};
#pragma unroll
            for (int k = 0; k < WIN; ++k) {
                const int ii = i - 5 + k;
                if (ii >= 0 && ii < TSIZE) {
                    const float gk = gw.g[k];
                    const f4 t4 = *(const f4*)&tp[SWZ4(ii, jq)];
#pragma unroll
                    for (int q = 0; q < 4; ++q) cxy[q] += gk * t4.v[q];
                }
            }
            const f4 mu1 = *(const f4*)&mus[po + e4];
            const f4 mu2 = *(const f4*)&mus[go + e4];
            const f4 q1  = *(const f4*)&gsqs[po + e4];
            const f4 q2  = *(const f4*)&gsqs[go + e4];
#pragma unroll
            for (int q = 0; q < 4; ++q) {
                const float m1 = mu1.v[q], m2 = mu2.v[q];
                const float m1s = m1 * m1, m2s = m2 * m2, m12 = m1 * m2;
                const float s1  = q1.v[q] - m1s;
                const float s2  = q2.v[q] - m2s;
                const float s12 = cxy[q] - m12;
                const float num = (2.0f * m12 + C1F) * (2.0f * s12 + C2F);
                const float den = (m1s + m2s + C1F) * (s1 + s2 + C2F);
                const float ssim = num / den;
                lsum += fabsf(xv.v[q] / 255.0f - yv.v[q] / 255.0f) + (1.0f - ssim);
            }
        }

        bsum += lsum;
        __syncthreads();   // protect tp reuse on next iteration
    }

    // block reduce once at the end; one scaled atomic per block
#pragma unroll
    for (int off = 32; off > 0; off >>= 1) bsum += __shfl_down(bsum, off);
    if (lane == 0) wred[tid >> 6] = bsum;
    __syncthreads();
    if (tid == 0) {
        const float total = wred[0] + wred[1] + wred[2] + wred[3];
        if (total != 0.0f) atomicAdd(out, total * inv_den);
    }
}

extern "C" void kernel_launch(void* const* d_in, const int* in_sizes, int n_in,
                              void* d_out, int out_size, void* d_ws, size_t ws_size,
                              hipStream_t stream) {
    const float* gt_boxes   = (const float*)d_in[0];  // (8,16,4)
    const float* pred_boxes = (const float*)d_in[1];  // (8,64,4)
    const float* imgs       = (const float*)d_in[2];  // (8,3,640,640)

    GaussW gw;
    {
        double gd[WIN]; double s = 0.0;
        for (int k = 0; k < WIN; ++k) {
            const double d = (double)(k - WIN / 2);
            gd[k] = exp(-(d * d) / (2.0 * 1.5 * 1.5));
            s += gd[k];
        }
        for (int k = 0; k < WIN; ++k) gw.g[k] = (float)(gd[k] / s);
    }

    float* ws = (float*)d_ws;
    float* patches = ws;                               // 640*3072
    float* mus     = patches + (size_t)NBOX * 3072;
    float* gsqs    = mus     + (size_t)NBOX * 3072;
    int* pair_list = (int*)(gsqs + (size_t)NBOX * 3072);  // 8192
    int* pair_cnt  = pair_list + NPAIR;                   // 32

    gen_patches<<<NBOX * 3 + NCOMP, 256, 0, stream>>>(
        gt_boxes, pred_boxes, imgs, patches, mus, gsqs,
        pair_list, pair_cnt, (float*)d_out, gw);

    pair_kernel<<<K2GRID, 256, 0, stream>>>(
        patches, mus, gsqs, pair_list, pair_cnt, (float*)d_out, gw);
}

// Round 9
// 100.296 us; speedup vs baseline: 1.1277x; 1.1253x over previous
//
#include <hip/hip_runtime.h>
#include <math.h>

#define TSIZE 32
#define WIN 11
#define NB 8
#define NG 16
#define NP 64
#define IMH 640
#define IMW 640
#define NBOX 640          // 128 gt + 512 pred
#define NPAIR 8192        // 8*16*64
#define NCOMP (NPAIR/256) // 32 compaction blocks
#define K2GRID 1536

#define C1F 6.5025f
#define C2F 58.5225f

// group-rotate swizzle for 32x32 f32 tiles in LDS: row i, col-group jq(0..7)
// physical f4 slot = ((jq + i) & 7). Col-conv b128 reads cover all 32 banks
// per 8-lane row phase -> conflict-free; same for writes.
#define SWZ4(row, jq) (((row) << 5) + ((((jq) + (row)) & 7) << 2))

struct GaussW { float g[WIN]; };
struct f4 { float v[4]; };

__device__ __forceinline__ float shl(float v, int src) {
    src = src < 0 ? 0 : (src > 63 ? 63 : src);
    return __shfl(v, src, 64);
}

// Build 14-tap row window (cols j4-5 .. j4+8, zero outside [0,32)) from
// per-thread f4 via intra-row shuffles. t = lane&7 (col group in row).
__device__ __forceinline__ void row_window(
    const float* __restrict__ own, int lane, int t, float* __restrict__ pv)
{
    const int l = lane;
    const float a0 = shl(own[0], l - 1), a1 = shl(own[1], l - 1);
    const float a2 = shl(own[2], l - 1), a3 = shl(own[3], l - 1);
    const float b0 = shl(own[0], l + 1), b1 = shl(own[1], l + 1);
    const float b2 = shl(own[2], l + 1), b3 = shl(own[3], l + 1);
    const float m3 = shl(own[3], l - 2);   // col j4-5
    const float p0 = shl(own[0], l + 2);   // col j4+8
    const bool vm1 = (t >= 1), vm2 = (t >= 2);
    const bool vp1 = (t <= 6), vp2 = (t <= 5);
    pv[0]  = vm2 ? m3 : 0.0f;
    pv[1]  = vm1 ? a0 : 0.0f;
    pv[2]  = vm1 ? a1 : 0.0f;
    pv[3]  = vm1 ? a2 : 0.0f;
    pv[4]  = vm1 ? a3 : 0.0f;
    pv[5]  = own[0]; pv[6] = own[1]; pv[7] = own[2]; pv[8] = own[3];
    pv[9]  = vp1 ? b0 : 0.0f;
    pv[10] = vp1 ? b1 : 0.0f;
    pv[11] = vp1 ? b2 : 0.0f;
    pv[12] = vp1 ? b3 : 0.0f;
    pv[13] = vp2 ? p0 : 0.0f;
}

// ---------------------------------------------------------------------------
// K1: blocks [0,1920): one block per (box,channel): pipelined crop staging ->
// LDS, bilinear -> regs, shuffle row conv, swizzled-LDS col conv.
// blocks [1920,1952): parallel ballot-compaction into per-block sublists
// (no atomics, no zero-init, no fences).
// ---------------------------------------------------------------------------
__global__ __launch_bounds__(256) void gen_patches(
    const float* __restrict__ gt_boxes, const float* __restrict__ pred_boxes,
    const float* __restrict__ imgs,
    float* __restrict__ patches, float* __restrict__ mus, float* __restrict__ gsqs,
    int* __restrict__ pair_list, int* __restrict__ pair_cnt, GaussW gw)
{
    const int bid = blockIdx.x;
    const int tid = threadIdx.x;

    if (bid >= NBOX * 3) {
        // ---- per-block ballot compaction ----
        const int blk = bid - NBOX * 3;          // [0, 32)
        const int p = blk * 256 + tid;           // [0, 8192)
        const int b  = p >> 10;
        const int gi = (p >> 6) & 15;
        const int pi = p & 63;
        bool mask;
        {
#pragma clang fp contract(off)
            const float* gb = gt_boxes  + ((size_t)b * NG + gi) * 4;
            const float* pb = pred_boxes + ((size_t)b * NP + pi) * 4;
            const float gx = gb[0], gy = gb[1], gw_ = gb[2], gh = gb[3];
            const float px = pb[0], py = pb[1], pw = pb[2], ph = pb[3];
            const float tlx = fmaxf(gx - gw_ / 2.0f, px - pw / 2.0f);
            const float tly = fmaxf(gy - gh / 2.0f, py - ph / 2.0f);
            const float brx = fminf(gx + gw_ / 2.0f, px + pw / 2.0f);
            const float bry = fminf(gy + gh / 2.0f, py + ph / 2.0f);
            const float en = ((tlx < brx) ? 1.0f : 0.0f) * ((tly < bry) ? 1.0f : 0.0f);
            const float ai = ((brx - tlx) * (bry - tly)) * en;
            const float ag = gw_ * gh;
            const float ap = pw * ph;
            const float iou = ai / (ag + ap - ai + 1e-16f);
            mask = (iou > 0.3f) && (pw > 2.0f) && (ph > 2.0f);
        }
        __shared__ int wcnt[4], woff[4];
        const unsigned long long bal = __ballot(mask);
        const int lane = tid & 63, wid = tid >> 6;
        if (lane == 0) wcnt[wid] = __popcll(bal);
        __syncthreads();
        if (tid == 0) {
            int s = 0;
#pragma unroll
            for (int w = 0; w < 4; ++w) { woff[w] = s; s += wcnt[w]; }
            pair_cnt[blk] = s;
        }
        __syncthreads();
        if (mask) {
            const int pre = __popcll(bal & ((1ull << lane) - 1ull));
            pair_list[blk * 256 + woff[wid] + pre] = p;
        }
        return;
    }

    // ---- patch generation ----
    const int box = bid / 3;
    const int c   = bid - box * 3;
    int b;
    const float* boxp;
    if (box < NB * NG) {
        b = box >> 4;
        boxp = gt_boxes + (size_t)box * 4;
    } else {
        const int q = box - NB * NG;
        b = q >> 6;
        boxp = pred_boxes + (size_t)q * 4;
    }
    const float* __restrict__ ic = imgs + ((size_t)b * 3 + c) * (IMH * IMW);
    float* __restrict__ patch_o = patches + ((size_t)box * 3 + c) * 1024;
    float* __restrict__ mu_o    = mus     + ((size_t)box * 3 + c) * 1024;
    float* __restrict__ gsq_o   = gsqs    + ((size_t)box * 3 + c) * 1024;

    __shared__ int   s_ylo[TSIZE], s_yhi[TSIZE], s_xlo[TSIZE], s_xhi[TSIZE];
    __shared__ float s_wy[TSIZE], s_wx[TSIZE];
    __shared__ __align__(16) float smem[4704];  // crop region; later ta/tb
    float* const ta = smem;
    float* const tb = smem + 1024;

    {
#pragma clang fp contract(off)
        const float b0 = boxp[0], b1 = boxp[1], b2 = boxp[2], b3 = boxp[3];
        const float x0 = floorf(b0), y0 = floorf(b1);
        const float w = floorf(b0 + b2) - x0;
        const float h = floorf(b1 + b3) - y0;

        if (tid < TSIZE) {
            const int t = tid;
            const float hm = fmaxf(h - 1.0f, 0.0f);
            const float scale = h / 32.0f;
            float ys = ((float)t + 0.5f) * scale - 0.5f;
            ys = fminf(fmaxf(ys, 0.0f), hm);
            const float yf = floorf(ys);
            s_wy[t] = ys - yf;
            const float ylo = yf + y0;
            const float yhi = fminf(yf + 1.0f, hm) + y0;
            s_ylo[t] = (int)fminf(fmaxf(ylo, 0.0f), (float)(IMH - 1));
            s_yhi[t] = (int)fminf(fmaxf(yhi, 0.0f), (float)(IMH - 1));
        } else if (tid < 2 * TSIZE) {
            const int t = tid - TSIZE;
            const float wm = fmaxf(w - 1.0f, 0.0f);
            const float scale = w / 32.0f;
            float xs = ((float)t + 0.5f) * scale - 0.5f;
            xs = fminf(fmaxf(xs, 0.0f), wm);
            const float xf = floorf(xs);
            s_wx[t] = xs - xf;
            const float xlo = xf + x0;
            const float xhi = fminf(xf + 1.0f, wm) + x0;
            s_xlo[t] = (int)fminf(fmaxf(xlo, 0.0f), (float)(IMW - 1));
            s_xhi[t] = (int)fminf(fmaxf(xhi, 0.0f), (float)(IMW - 1));
        }
    }
    __syncthreads();

    // stage crop region: two-phase (all loads in flight, then LDS writes)
    const int ry0 = s_ylo[0], ry1 = s_yhi[31];
    const int rx0 = s_xlo[0], rx1 = s_xhi[31];
    const int RH = ry1 - ry0 + 1;                // <= 69
    const int RW = rx1 - rx0 + 1;                // <= 69
    const int stride = RW | 1;
    const int wv = tid >> 6, lane = tid & 63;
    {
        float rbuf[18];
        const bool cl = lane < RW;
#pragma unroll
        for (int u = 0; u < 18; ++u) {
            const int r = wv + (u << 2);
            rbuf[u] = (r < RH && cl)
                      ? ic[(size_t)(ry0 + r) * IMW + rx0 + lane] : 0.0f;
        }
        const bool c2 = (64 + lane) < RW;        // rare tail cols
#pragma unroll
        for (int u = 0; u < 18; ++u) {
            const int r = wv + (u << 2);
            if (r < RH) {
                if (cl) smem[r * stride + lane] = rbuf[u];
                if (c2) smem[r * stride + 64 + lane] =
                            ic[(size_t)(ry0 + r) * IMW + rx0 + 64 + lane];
            }
        }
    }
    __syncthreads();

    const int i  = tid >> 3;            // row 0..31 (8 threads per row)
    const int t  = tid & 7;             // col group in row
    const int j4 = t << 2;
    const int jq = t;
    const int e4 = (i << 5) + j4;

    // bilinear from LDS crop -> registers
    float vv[4];
    {
        const int yl = s_ylo[i] - ry0, yh = s_yhi[i] - ry0;
        const float wy = s_wy[i];
#pragma unroll
        for (int q = 0; q < 4; ++q) {
#pragma clang fp contract(off)
            const int j = j4 + q;
            const int xl = s_xlo[j] - rx0, xh = s_xhi[j] - rx0;
            const float wx = s_wx[j];
            const float tl = smem[yl * stride + xl], tr = smem[yl * stride + xh];
            const float bl = smem[yh * stride + xl], br = smem[yh * stride + xh];
            const float top = tl * (1.0f - wx) + tr * wx;
            const float bot = bl * (1.0f - wx) + br * wx;
            vv[q] = top * (1.0f - wy) + bot * wy;
        }
    }
    __syncthreads();   // all crop reads done before aliasing smem as ta/tb

    {
        f4 o; o.v[0] = vv[0]; o.v[1] = vv[1]; o.v[2] = vv[2]; o.v[3] = vv[3];
        *(f4*)&patch_o[e4] = o;
    }

    // row conv (val, val^2) via shuffles -> swizzled ta/tb
    {
        float pv[14];
        row_window(vv, lane, t, pv);
        float am[4] = {0.f,0.f,0.f,0.f}, aq[4] = {0.f,0.f,0.f,0.f};
#pragma unroll
        for (int k = 0; k < WIN; ++k) {
            const float gk = gw.g[k];
#pragma unroll
            for (int q = 0; q < 4; ++q) {
                const float v = pv[k + q];
                am[q] += gk * v;
                aq[q] += gk * (v * v);
            }
        }
        f4 oa, ob;
#pragma unroll
        for (int q = 0; q < 4; ++q) { oa.v[q] = am[q]; ob.v[q] = aq[q]; }
        *(f4*)&ta[SWZ4(i, jq)] = oa;
        *(f4*)&tb[SWZ4(i, jq)] = ob;
    }
    __syncthreads();

    // col conv from swizzled LDS (b128, conflict-free)
    {
        float cm[4] = {0.f,0.f,0.f,0.f}, cq[4] = {0.f,0.f,0.f,0.f};
#pragma unroll
        for (int k = 0; k < WIN; ++k) {
            const int ii = i - 5 + k;
            if (ii >= 0 && ii < TSIZE) {
                const float gk = gw.g[k];
                const f4 m4 = *(const f4*)&ta[SWZ4(ii, jq)];
                const f4 s4 = *(const f4*)&tb[SWZ4(ii, jq)];
#pragma unroll
                for (int q = 0; q < 4; ++q) {
                    cm[q] += gk * m4.v[q];
                    cq[q] += gk * s4.v[q];
                }
            }
        }
        f4 om, oq;
#pragma unroll
        for (int q = 0; q < 4; ++q) { om.v[q] = cm[q]; oq.v[q] = cq[q]; }
        *(f4*)&mu_o[e4]  = om;
        *(f4*)&gsq_o[e4] = oq;
    }
}

// ---------------------------------------------------------------------------
// K2: grid-stride over (active pair, channel). Wave-0 shuffle-prefix of the
// 32 per-block counts; x,y in registers; xy row conv via shuffles; swizzled-
// LDS col conv; fused SSIM+L1. Per-thread accumulation across items; ONE
// block reduce at the end; partial[blockIdx.x] plain store (fully written,
// no memset, no atomics, no fences).
// ---------------------------------------------------------------------------
__global__ __launch_bounds__(256) void pair_kernel(
    const float* __restrict__ patches, const float* __restrict__ mus,
    const float* __restrict__ gsqs,
    const int* __restrict__ pair_list, const int* __restrict__ pair_cnt,
    float* __restrict__ partial, GaussW gw)
{
    __shared__ __align__(16) float tp[1024];
    __shared__ float wred[4];
    __shared__ int cum[NCOMP + 1];
    const int tid = threadIdx.x;
    const int lane = tid & 63;

    // parallel prefix of 32 counts in wave 0 (~50 cyc)
    if (tid < 64) {
        int v = (lane < NCOMP) ? pair_cnt[lane] : 0;
#pragma unroll
        for (int d = 1; d < 32; d <<= 1) {
            const int u = __shfl_up(v, d, 64);
            if ((lane & 31) >= d) v += u;
        }
        if (lane < NCOMP) cum[lane + 1] = v;   // inclusive prefix
        if (lane == 0) cum[0] = 0;
    }
    __syncthreads();
    const int nw = cum[NCOMP] * 3;

    const int i  = tid >> 3;
    const int t  = tid & 7;
    const int j4 = t << 2;
    const int jq = t;
    const int e4 = (i << 5) + j4;

    float bsum = 0.0f;   // per-thread accumulation across this block's items

    for (int w = blockIdx.x; w < nw; w += gridDim.x) {
        const int k3 = w / 3;
        const int c  = w - k3 * 3;
        int s = 0;
        while (cum[s + 1] <= k3) ++s;           // block-uniform, <=32 iters
        const int p  = pair_list[s * 256 + (k3 - cum[s])];
        const int b  = p >> 10;
        const int gi = (p >> 6) & 15;
        const int pi = p & 63;
        const int gbox = b * NG + gi;
        const int pbox = NB * NG + b * NP + pi;
        const size_t po = ((size_t)pbox * 3 + c) * 1024;
        const size_t go = ((size_t)gbox * 3 + c) * 1024;

        const f4 xv = *(const f4*)&patches[po + e4];
        const f4 yv = *(const f4*)&patches[go + e4];

        // row conv of x*y via shuffles -> swizzled tp
        {
            float prod[4];
#pragma unroll
            for (int q = 0; q < 4; ++q) prod[q] = xv.v[q] * yv.v[q];
            float pv[14];
            row_window(prod, lane, t, pv);
            float a[4] = {0.f,0.f,0.f,0.f};
#pragma unroll
            for (int k = 0; k < WIN; ++k) {
                const float gk = gw.g[k];
#pragma unroll
                for (int q = 0; q < 4; ++q) a[q] += gk * pv[k + q];
            }
            f4 o;
#pragma unroll
            for (int q = 0; q < 4; ++q) o.v[q] = a[q];
            *(f4*)&tp[SWZ4(i, jq)] = o;
        }
        __syncthreads();

        // col conv + fused epilogue
        {
            float cxy[4] = {0.f,0.f,0.f,0.f};
#pragma unroll
            for (int k = 0; k < WIN; ++k) {
                const int ii = i - 5 + k;
                if (ii >= 0 && ii < TSIZE) {
                    const float gk = gw.g[k];
                    const f4 t4 = *(const f4*)&tp[SWZ4(ii, jq)];
#pragma unroll
                    for (int q = 0; q < 4; ++q) cxy[q] += gk * t4.v[q];
                }
            }
            const f4 mu1 = *(const f4*)&mus[po + e4];
            const f4 mu2 = *(const f4*)&mus[go + e4];
            const f4 q1  = *(const f4*)&gsqs[po + e4];
            const f4 q2  = *(const f4*)&gsqs[go + e4];
#pragma unroll
            for (int q = 0; q < 4; ++q) {
                const float m1 = mu1.v[q], m2 = mu2.v[q];
                const float m1s = m1 * m1, m2s = m2 * m2, m12 = m1 * m2;
                const float s1  = q1.v[q] - m1s;
                const float s2  = q2.v[q] - m2s;
                const float s12 = cxy[q] - m12;
                const float num = (2.0f * m12 + C1F) * (2.0f * s12 + C2F);
                const float den = (m1s + m2s + C1F) * (s1 + s2 + C2F);
                const float ssim = num / den;
                bsum += fabsf(xv.v[q] / 255.0f - yv.v[q] / 255.0f) + (1.0f - ssim);
            }
        }
        __syncthreads();   // protect tp reuse on next iteration
    }

    // one block reduce at the end; plain store (no atomic)
#pragma unroll
    for (int off = 32; off > 0; off >>= 1) bsum += __shfl_down(bsum, off);
    if (lane == 0) wred[tid >> 6] = bsum;
    __syncthreads();
    if (tid == 0) partial[blockIdx.x] = wred[0] + wred[1] + wred[2] + wred[3];
}

__global__ __launch_bounds__(256) void finalize_kernel(
    const int* __restrict__ pair_cnt, const float* __restrict__ partial,
    float* __restrict__ out)
{
    __shared__ float wred[4];
    const int tid = threadIdx.x;
    int n = 0;
#pragma unroll
    for (int k = 0; k < NCOMP; ++k) n += pair_cnt[k];
    float lsum = 0.0f;
    for (int w = tid; w < K2GRID; w += 256) lsum += partial[w];
#pragma unroll
    for (int off = 32; off > 0; off >>= 1) lsum += __shfl_down(lsum, off);
    if ((tid & 63) == 0) wred[tid >> 6] = lsum;
    __syncthreads();
    if (tid == 0) {
        const float total = wred[0] + wred[1] + wred[2] + wred[3];
        out[0] = (n > 0) ? (total / ((float)n * 3072.0f)) : 0.0f;
    }
}

extern "C" void kernel_launch(void* const* d_in, const int* in_sizes, int n_in,
                              void* d_out, int out_size, void* d_ws, size_t ws_size,
                              hipStream_t stream) {
    const float* gt_boxes   = (const float*)d_in[0];  // (8,16,4)
    const float* pred_boxes = (const float*)d_in[1];  // (8,64,4)
    const float* imgs       = (const float*)d_in[2];  // (8,3,640,640)

    GaussW gw;
    {
        double gd[WIN]; double s = 0.0;
        for (int k = 0; k < WIN; ++k) {
            const double d = (double)(k - WIN / 2);
            gd[k] = exp(-(d * d) / (2.0 * 1.5 * 1.5));
            s += gd[k];
        }
        for (int k = 0; k < WIN; ++k) gw.g[k] = (float)(gd[k] / s);
    }

    float* ws = (float*)d_ws;
    float* patches = ws;                               // 640*3072
    float* mus     = patches + (size_t)NBOX * 3072;
    float* gsqs    = mus     + (size_t)NBOX * 3072;
    float* partial = gsqs    + (size_t)NBOX * 3072;    // K2GRID floats
    int* pair_list = (int*)(partial + K2GRID);         // 8192
    int* pair_cnt  = pair_list + NPAIR;                // 32

    gen_patches<<<NBOX * 3 + NCOMP, 256, 0, stream>>>(
        gt_boxes, pred_boxes, imgs, patches, mus, gsqs, pair_list, pair_cnt, gw);

    pair_kernel<<<K2GRID, 256, 0, stream>>>(
        patches, mus, gsqs, pair_list, pair_cnt, partial, gw);

    finalize_kernel<<<1, 256, 0, stream>>>(pair_cnt, partial, (float*)d_out);
}